// Round 3
// baseline (139.283 us; speedup 1.0000x reference)
//
#include <hip/hip_runtime.h>
#include <hip/hip_bf16.h>

#define S_ 1024
#define D_ 128
#define V_ 100000
#define N_ 4096
#define VPAD_ 100096    // 1564 * 64
#define NT64_ 1564      // number of 64-row K tiles
#define NSPLIT_ 32

typedef __attribute__((ext_vector_type(4))) float f32x4;
typedef __attribute__((ext_vector_type(8))) short bf16x8;

#define LOG2E_ 1.4426950408889634f
#define LN2_   0.6931471805599453f

__device__ __forceinline__ void gload16(const void* g, void* l) {
    __builtin_amdgcn_global_load_lds(
        (const __attribute__((address_space(1))) void*)g,
        (__attribute__((address_space(3))) void*)l, 16, 0, 0);
}

__device__ __forceinline__ float exp2_fast(float x) {
#if __has_builtin(__builtin_amdgcn_exp2f)
    return __builtin_amdgcn_exp2f(x);
#else
    return exp2f(x);
#endif
}

// ---- kernel 1: normalize K rows -> bf16, zero-fill pad rows [V_, VPAD_) ----
__global__ void knorm_kernel(const float* __restrict__ K, __hip_bfloat16* __restrict__ Kn) {
    int w = (blockIdx.x * blockDim.x + threadIdx.x) >> 6;
    int lane = threadIdx.x & 63;
    if (w >= VPAD_) return;
    unsigned int* dst = (unsigned int*)(Kn + (size_t)w * D_);
    if (w >= V_) { dst[lane] = 0u; return; }
    float2 v = ((const float2*)(K + (size_t)w * D_))[lane];
    float ss = v.x * v.x + v.y * v.y;
    #pragma unroll
    for (int off = 32; off; off >>= 1) ss += __shfl_xor(ss, off);
    float rn = rsqrtf(ss);
    __hip_bfloat162 o;
    o.x = __float2bfloat16(v.x * rn);
    o.y = __float2bfloat16(v.y * rn);
    ((__hip_bfloat162*)dst)[lane] = o;
}

// ---- kernel 2: gather + normalize Q rows -> bf16, PRE-SCALED by log2(e) ----
__global__ void qnorm_kernel(const float* __restrict__ Q, const int* __restrict__ loc,
                             __hip_bfloat16* __restrict__ Qn) {
    int w = (blockIdx.x * blockDim.x + threadIdx.x) >> 6;
    int lane = threadIdx.x & 63;
    if (w >= N_) return;
    int b = loc[2 * w], s = loc[2 * w + 1];
    float2 v = ((const float2*)(Q + ((size_t)b * S_ + (size_t)s) * D_))[lane];
    float ss = v.x * v.x + v.y * v.y;
    #pragma unroll
    for (int off = 32; off; off >>= 1) ss += __shfl_xor(ss, off);
    float rn = rsqrtf(ss) * LOG2E_;   // fold log2(e): logits land in exp2 domain
    __hip_bfloat162 o;
    o.x = __float2bfloat16(v.x * rn);
    o.y = __float2bfloat16(v.y * rn);
    ((__hip_bfloat162*)(Qn + (size_t)w * D_))[lane] = o;
}

__global__ void zeroS_kernel(float* __restrict__ S) {
    S[blockIdx.x * 256 + threadIdx.x] = 0.f;
}

// ---- kernel 3: main  sum_v exp2(q . k_v)  via bf16 MFMA ----
// grid (32, NSPLIT_), block 256 = 4 waves. Block tile: 128 q-rows x 64 v-cols.
// Each wave: 32 q-rows x 64 v-cols (m=2, nn=4); K-fragments shared by all waves.
// K tile = 64 rows x 128 d = 16KB, double-buffered (32KB LDS -> 4 blocks/CU).
// LDS in FRAGMENT ORDER: chunk(nn,kk)=nn*4+kk, LDS[chunk*1024 + lane*16] is the
// exact ds_read_b128 payload -> linear, zero bank conflicts.
__global__ __launch_bounds__(256, 4) void ce_main(
    const __hip_bfloat16* __restrict__ Qn,
    const __hip_bfloat16* __restrict__ Kn,
    float* __restrict__ Ssum)
{
    __shared__ char klds[32768];   // 2 x 16KB double buffer

    const int tid  = threadIdx.x;
    const int lane = tid & 63;
    const int wv   = tid >> 6;     // wave id 0..3
    const int nb = blockIdx.x;
    const int split = blockIdx.y;

    // staging: thread covers chunk = it*4 + wv (it=0..3), i.e. nn=it, kk=wv
    // G(chunk,lane) = (nn*16 + (lane&15))*256 + kk*64 + (lane>>4)*16
    const int goff = ((lane & 15) << 8) + (wv << 6) + ((lane >> 4) << 4);
    const int loff = (wv << 10) + (lane << 4);

    // ---- Q fragments -> registers (loop-invariant), direct from global ----
    // wave wv owns q-rows [nb*128 + wv*32, +32)
    bf16x8 afr[2][4];
    {
        const char* qsrc = (const char*)Qn + (size_t)nb * 32768
                         + (wv * 32 + (lane & 15)) * 256 + ((lane >> 4) << 4);
        #pragma unroll
        for (int m = 0; m < 2; ++m)
            #pragma unroll
            for (int kk = 0; kk < 4; ++kk)
                afr[m][kk] = *(const bf16x8*)(qsrc + m * 4096 + kk * 64);
    }

    // ---- prologue: stage first K tile into buffer 0 ----
    {
        const char* src = (const char*)Kn + (size_t)split * 16384 + goff;
        #pragma unroll
        for (int it = 0; it < 4; ++it)
            gload16(src + it * 4096, klds + loff + it * 4096);
    }

    float psum[2][4];
    #pragma unroll
    for (int m = 0; m < 2; ++m)
        #pragma unroll
        for (int q = 0; q < 4; ++q) psum[m][q] = 0.f;

    __syncthreads();   // implicit vmcnt(0): buffer 0 ready

    int cur = 0;
    for (int t = split; t < NT64_; t += NSPLIT_) {
        // stage next tile into the other buffer (loads fly during compute)
        int tn = t + NSPLIT_;
        if (tn < NT64_) {
            const char* src = (const char*)Kn + (size_t)tn * 16384 + goff;
            char* dst = klds + ((cur ^ 1) << 14) + loff;
            #pragma unroll
            for (int it = 0; it < 4; ++it)
                gload16(src + it * 4096, dst + it * 4096);
        }

        const char* base = klds + (cur << 14) + (lane << 4);
        f32x4 acc[2][4];
        #pragma unroll
        for (int m = 0; m < 2; ++m)
            #pragma unroll
            for (int nn = 0; nn < 4; ++nn) acc[m][nn] = (f32x4){0.f, 0.f, 0.f, 0.f};

        #pragma unroll
        for (int kk = 0; kk < 4; ++kk) {
            bf16x8 bfrk[4];
            #pragma unroll
            for (int nn = 0; nn < 4; ++nn)
                bfrk[nn] = *(const bf16x8*)(base + nn * 4096 + kk * 1024);
            #pragma unroll
            for (int m = 0; m < 2; ++m)
                #pragma unroll
                for (int nn = 0; nn < 4; ++nn)
                    acc[m][nn] = __builtin_amdgcn_mfma_f32_16x16x32_bf16(
                        afr[m][kk], bfrk[nn], acc[m][nn], 0, 0, 0);
        }

        #pragma unroll
        for (int m = 0; m < 2; ++m)
            #pragma unroll
            for (int nn = 0; nn < 4; ++nn)
                #pragma unroll
                for (int q = 0; q < 4; ++q)
                    psum[m][q] += exp2_fast(acc[m][nn][q]);   // logits bounded: no max

        __syncthreads();   // drains vmcnt: next buffer ready, this one reusable
        cur ^= 1;
    }

    // reduce over the 16 lanes holding the same rows (different cols), then atomics
    #pragma unroll
    for (int m = 0; m < 2; ++m) {
        #pragma unroll
        for (int q = 0; q < 4; ++q) {
            float v = psum[m][q];
            v += __shfl_xor(v, 1);
            v += __shfl_xor(v, 2);
            v += __shfl_xor(v, 4);
            v += __shfl_xor(v, 8);
            if ((lane & 15) == 0) {
                int row = nb * 128 + wv * 32 + m * 16 + ((lane >> 4) << 2) + q;
                atomicAdd(&Ssum[row], v);
            }
        }
    }
}

// ---- kernel 4: per-row term = log(S - 96) - true_logit ----
// Qn is scaled by log2(e): true_logit = (qn . k) * ln2
__global__ void term_kernel(const __hip_bfloat16* __restrict__ Qn,
                            const __hip_bfloat16* __restrict__ Kn,
                            const int* __restrict__ labels,
                            const float* __restrict__ Ssum,
                            float* __restrict__ T) {
    int w = (blockIdx.x * blockDim.x + threadIdx.x) >> 6;
    int lane = threadIdx.x & 63;
    if (w >= N_) return;
    int lab = labels[w];
    __hip_bfloat162 q2 = ((const __hip_bfloat162*)(Qn + (size_t)w * D_))[lane];
    __hip_bfloat162 k2 = ((const __hip_bfloat162*)(Kn + (size_t)lab * D_))[lane];
    float d = __bfloat162float(q2.x) * __bfloat162float(k2.x)
            + __bfloat162float(q2.y) * __bfloat162float(k2.y);
    #pragma unroll
    for (int off = 32; off; off >>= 1) d += __shfl_xor(d, off);
    if (lane == 0) T[w] = logf(Ssum[w] - 96.0f) - d * LN2_;
}

// ---- kernel 5: mean over N ----
__global__ void reduce_kernel(const float* __restrict__ T, float* __restrict__ out) {
    __shared__ float sm[4];
    float s = 0.f;
    for (int i = threadIdx.x; i < N_; i += 256) s += T[i];
    #pragma unroll
    for (int off = 32; off; off >>= 1) s += __shfl_xor(s, off);
    if ((threadIdx.x & 63) == 0) sm[threadIdx.x >> 6] = s;
    __syncthreads();
    if (threadIdx.x == 0) out[0] = (sm[0] + sm[1] + sm[2] + sm[3]) * (1.0f / (float)N_);
}

extern "C" void kernel_launch(void* const* d_in, const int* in_sizes, int n_in,
                              void* d_out, int out_size, void* d_ws, size_t ws_size,
                              hipStream_t stream) {
    (void)in_sizes; (void)n_in; (void)out_size; (void)ws_size;
    const float* Q   = (const float*)d_in[0];
    const float* K   = (const float*)d_in[1];
    const int* loc   = (const int*)d_in[2];
    const int* labels= (const int*)d_in[3];
    float* out = (float*)d_out;

    char* ws = (char*)d_ws;
    __hip_bfloat16* Kn = (__hip_bfloat16*)ws;                       // VPAD_*128*2 = 25,624,576 B
    __hip_bfloat16* Qn = (__hip_bfloat16*)(ws + 25624576);          // N_*128*2   =  1,048,576 B
    float* Ssum        = (float*)(ws + 25624576 + 1048576);         // N_*4
    float* T           = Ssum + N_;                                  // N_*4

    knorm_kernel<<<VPAD_ / 4, 256, 0, stream>>>(K, Kn);
    qnorm_kernel<<<N_ / 4, 256, 0, stream>>>(Q, loc, Qn);
    zeroS_kernel<<<N_ / 256, 256, 0, stream>>>(Ssum);
    ce_main<<<dim3(N_ / 128, NSPLIT_), 256, 0, stream>>>(Qn, Kn, Ssum);
    term_kernel<<<N_ / 4, 256, 0, stream>>>(Qn, Kn, labels, Ssum, T);
    reduce_kernel<<<1, 256, 0, stream>>>(T, out);
}

// Round 4
// 130.693 us; speedup vs baseline: 1.0657x; 1.0657x over previous
//
#include <hip/hip_runtime.h>
#include <hip/hip_bf16.h>

#define S_ 1024
#define D_ 128
#define V_ 100000
#define N_ 4096
#define VPAD_ 100096    // 1564 * 64
#define NT64_ 1564      // number of 64-row K tiles
#define NSPLIT_ 24      // grid = 32 x 24 = 768 = 3 blocks/CU exactly

typedef __attribute__((ext_vector_type(4))) float f32x4;
typedef __attribute__((ext_vector_type(8))) short bf16x8;

#define LOG2E_ 1.4426950408889634f
#define LN2_   0.6931471805599453f

__device__ __forceinline__ void gload16(const void* g, void* l) {
    __builtin_amdgcn_global_load_lds(
        (const __attribute__((address_space(1))) void*)g,
        (__attribute__((address_space(3))) void*)l, 16, 0, 0);
}

__device__ __forceinline__ float exp2_fast(float x) {
#if __has_builtin(__builtin_amdgcn_exp2f)
    return __builtin_amdgcn_exp2f(x);
#else
    return exp2f(x);
#endif
}

// ---- kernel 1: normalize K rows -> bf16, zero-fill pad rows [V_, VPAD_) ----
__global__ void knorm_kernel(const float* __restrict__ K, __hip_bfloat16* __restrict__ Kn) {
    int w = (blockIdx.x * blockDim.x + threadIdx.x) >> 6;
    int lane = threadIdx.x & 63;
    if (w >= VPAD_) return;
    unsigned int* dst = (unsigned int*)(Kn + (size_t)w * D_);
    if (w >= V_) { dst[lane] = 0u; return; }
    float2 v = ((const float2*)(K + (size_t)w * D_))[lane];
    float ss = v.x * v.x + v.y * v.y;
    #pragma unroll
    for (int off = 32; off; off >>= 1) ss += __shfl_xor(ss, off);
    float rn = rsqrtf(ss);
    __hip_bfloat162 o;
    o.x = __float2bfloat16(v.x * rn);
    o.y = __float2bfloat16(v.y * rn);
    ((__hip_bfloat162*)dst)[lane] = o;
}

// ---- kernel 2: gather + normalize Q -> bf16 (pre-scaled by log2 e); zero Ssum ----
__global__ void qnorm_kernel(const float* __restrict__ Q, const int* __restrict__ loc,
                             __hip_bfloat16* __restrict__ Qn, float* __restrict__ Ssum) {
    int w = (blockIdx.x * blockDim.x + threadIdx.x) >> 6;
    int lane = threadIdx.x & 63;
    if (w >= N_) return;
    if (lane == 0) Ssum[w] = 0.f;          // re-zeroed every call (harness poisons ws)
    int b = loc[2 * w], s = loc[2 * w + 1];
    float2 v = ((const float2*)(Q + ((size_t)b * S_ + (size_t)s) * D_))[lane];
    float ss = v.x * v.x + v.y * v.y;
    #pragma unroll
    for (int off = 32; off; off >>= 1) ss += __shfl_xor(ss, off);
    float rn = rsqrtf(ss) * LOG2E_;        // exp2 domain
    __hip_bfloat162 o;
    o.x = __float2bfloat16(v.x * rn);
    o.y = __float2bfloat16(v.y * rn);
    ((__hip_bfloat162*)(Qn + (size_t)w * D_))[lane] = o;
}

// ---- kernel 3: main  sum_v exp2(q . k_v)  via bf16 MFMA ----
// grid (32, NSPLIT_) remapped so all nb-blocks of a split share an XCD.
// Block: 128q x 64v, 4 waves. Wave: 64q x 32v (m=4, nn=2) -> reads only its
// 8KB col-half per tile. K tile = 64 rows x 128 d = 16KB, double-buffered.
// LDS fragment order: chunk(nn,kk)=nn*4+kk at chunk*1024 + lane*16 (linear,
// conflict-free). Staging: thread's 4 chunks = wv*4+it -> global imm offsets
// {0,64,128,192}, LDS offsets it*1024.
__global__ __launch_bounds__(256, 3) void ce_main(
    const __hip_bfloat16* __restrict__ Qn,
    const __hip_bfloat16* __restrict__ Kn,
    float* __restrict__ Ssum)
{
    __shared__ char klds[32768];   // 2 x 16KB double buffer

    const int tid  = threadIdx.x;
    const int lane = tid & 63;
    const int wv   = tid >> 6;     // wave id 0..3
    const int wr   = wv >> 1;      // q-half
    const int wc   = wv & 1;       // col-half

    // XCD-aware remap: each XCD owns 4 whole splits (all 32 nb of each)
    const int fid  = blockIdx.y * 32 + blockIdx.x;
    const int xcd  = fid & 7;
    const int idx  = fid >> 3;               // 0..95
    const int split = xcd * 3 + (idx >> 5);  // NSPLIT_/8 = 3 splits per XCD
    const int nb    = idx & 31;

    // staging: chunk = wv*4 + it  (nn = wv>>... here nn = chunk>>2 = wv, kk = it)
    // G(chunk,lane) = (nn*16 + (lane&15))*256 + kk*64 + (lane>>4)*16
    const int goff = (wv << 12) + ((lane & 15) << 8) + ((lane >> 4) << 4);
    const int loff = (wv << 12) + (lane << 4);

    // ---- Q fragments -> registers (loop-invariant) ----
    bf16x8 afr[4][4];
    {
        const char* qsrc = (const char*)Qn + (size_t)nb * 32768
                         + (wr * 64 + (lane & 15)) * 256 + ((lane >> 4) << 4);
        #pragma unroll
        for (int m = 0; m < 4; ++m)
            #pragma unroll
            for (int kk = 0; kk < 4; ++kk)
                afr[m][kk] = *(const bf16x8*)(qsrc + m * 4096 + kk * 64);
    }

    // ---- prologue: stage first K tile into buffer 0 ----
    {
        const char* src = (const char*)Kn + (size_t)split * 16384 + goff;
        #pragma unroll
        for (int it = 0; it < 4; ++it)
            gload16(src + it * 64, klds + loff + it * 1024);
    }

    float psum[4][4];
    #pragma unroll
    for (int m = 0; m < 4; ++m)
        #pragma unroll
        for (int q = 0; q < 4; ++q) psum[m][q] = 0.f;

    const f32x4 fz = {0.f, 0.f, 0.f, 0.f};   // persistent zero C-operand

    __syncthreads();   // implicit vmcnt(0): buffer 0 ready

    int cur = 0;
    for (int t = split; t < NT64_; t += NSPLIT_) {
        // stage next tile into the other buffer (flies during compute)
        int tn = t + NSPLIT_;
        if (tn < NT64_) {
            const char* src = (const char*)Kn + (size_t)tn * 16384 + goff;
            char* dst = klds + ((cur ^ 1) << 14) + loff;
            #pragma unroll
            for (int it = 0; it < 4; ++it)
                gload16(src + it * 64, dst + it * 1024);
        }

        // wave reads only its col-half: chunks (wc*2+nn)*4+kk, base+imm offsets
        const char* base = klds + (cur << 14) + (wc << 13) + (lane << 4);
        f32x4 acc[4][2];

        __builtin_amdgcn_s_setprio(1);
        {   // kk = 0: C-operand = persistent zero regs (no acc re-init movs)
            bf16x8 b0 = *(const bf16x8*)(base);
            bf16x8 b1 = *(const bf16x8*)(base + 4096);
            #pragma unroll
            for (int m = 0; m < 4; ++m) {
                acc[m][0] = __builtin_amdgcn_mfma_f32_16x16x32_bf16(afr[m][0], b0, fz, 0, 0, 0);
                acc[m][1] = __builtin_amdgcn_mfma_f32_16x16x32_bf16(afr[m][0], b1, fz, 0, 0, 0);
            }
        }
        #pragma unroll
        for (int kk = 1; kk < 4; ++kk) {
            bf16x8 b0 = *(const bf16x8*)(base + kk * 1024);
            bf16x8 b1 = *(const bf16x8*)(base + 4096 + kk * 1024);
            #pragma unroll
            for (int m = 0; m < 4; ++m) {
                acc[m][0] = __builtin_amdgcn_mfma_f32_16x16x32_bf16(afr[m][kk], b0, acc[m][0], 0, 0, 0);
                acc[m][1] = __builtin_amdgcn_mfma_f32_16x16x32_bf16(afr[m][kk], b1, acc[m][1], 0, 0, 0);
            }
        }
        __builtin_amdgcn_s_setprio(0);

        #pragma unroll
        for (int m = 0; m < 4; ++m)
            #pragma unroll
            for (int q = 0; q < 4; ++q)
                psum[m][q] += exp2_fast(acc[m][0][q]) + exp2_fast(acc[m][1][q]);

        __syncthreads();   // next buffer staged, this one reusable
        cur ^= 1;
    }

    // reduce over 16 lanes (same rows, different cols), then atomics
    #pragma unroll
    for (int m = 0; m < 4; ++m) {
        #pragma unroll
        for (int q = 0; q < 4; ++q) {
            float v = psum[m][q];
            v += __shfl_xor(v, 1);
            v += __shfl_xor(v, 2);
            v += __shfl_xor(v, 4);
            v += __shfl_xor(v, 8);
            if ((lane & 15) == 0) {
                int row = nb * 128 + wr * 64 + m * 16 + ((lane >> 4) << 2) + q;
                atomicAdd(&Ssum[row], v);
            }
        }
    }
}

// ---- kernel 4: per-row term = log(S - 96) - true_logit ----
__global__ void term_kernel(const __hip_bfloat16* __restrict__ Qn,
                            const __hip_bfloat16* __restrict__ Kn,
                            const int* __restrict__ labels,
                            const float* __restrict__ Ssum,
                            float* __restrict__ T) {
    int w = (blockIdx.x * blockDim.x + threadIdx.x) >> 6;
    int lane = threadIdx.x & 63;
    if (w >= N_) return;
    int lab = labels[w];
    __hip_bfloat162 q2 = ((const __hip_bfloat162*)(Qn + (size_t)w * D_))[lane];
    __hip_bfloat162 k2 = ((const __hip_bfloat162*)(Kn + (size_t)lab * D_))[lane];
    float d = __bfloat162float(q2.x) * __bfloat162float(k2.x)
            + __bfloat162float(q2.y) * __bfloat162float(k2.y);
    #pragma unroll
    for (int off = 32; off; off >>= 1) d += __shfl_xor(d, off);
    if (lane == 0) T[w] = logf(Ssum[w] - 96.0f) - d * LN2_;
}

// ---- kernel 5: mean over N ----
__global__ void reduce_kernel(const float* __restrict__ T, float* __restrict__ out) {
    __shared__ float sm[4];
    float s = 0.f;
    for (int i = threadIdx.x; i < N_; i += 256) s += T[i];
    #pragma unroll
    for (int off = 32; off; off >>= 1) s += __shfl_xor(s, off);
    if ((threadIdx.x & 63) == 0) sm[threadIdx.x >> 6] = s;
    __syncthreads();
    if (threadIdx.x == 0) out[0] = (sm[0] + sm[1] + sm[2] + sm[3]) * (1.0f / (float)N_);
}

extern "C" void kernel_launch(void* const* d_in, const int* in_sizes, int n_in,
                              void* d_out, int out_size, void* d_ws, size_t ws_size,
                              hipStream_t stream) {
    (void)in_sizes; (void)n_in; (void)out_size; (void)ws_size;
    const float* Q   = (const float*)d_in[0];
    const float* K   = (const float*)d_in[1];
    const int* loc   = (const int*)d_in[2];
    const int* labels= (const int*)d_in[3];
    float* out = (float*)d_out;

    char* ws = (char*)d_ws;
    __hip_bfloat16* Kn = (__hip_bfloat16*)ws;                       // VPAD_*128*2 = 25,624,576 B
    __hip_bfloat16* Qn = (__hip_bfloat16*)(ws + 25624576);          // N_*128*2   =  1,048,576 B
    float* Ssum        = (float*)(ws + 25624576 + 1048576);         // N_*4
    float* T           = Ssum + N_;                                  // N_*4

    knorm_kernel<<<VPAD_ / 4, 256, 0, stream>>>(K, Kn);
    qnorm_kernel<<<N_ / 4, 256, 0, stream>>>(Q, loc, Qn, Ssum);
    ce_main<<<dim3(32, NSPLIT_), 256, 0, stream>>>(Qn, Kn, Ssum);
    term_kernel<<<N_ / 4, 256, 0, stream>>>(Qn, Kn, labels, Ssum, T);
    reduce_kernel<<<1, 256, 0, stream>>>(T, out);
}